// Round 1
// baseline (899.912 us; speedup 1.0000x reference)
//
#include <hip/hip_runtime.h>
#include <cstdint>

// Problem constants (fixed by setup_inputs: data (96,256,64,64) fp32, p=2)
#define NB 8            // batches (96/12)
#define NC 256          // channels
#define FH 64           // face H=W
#define OW 68           // padded width/height (64 + 2*2)
#define IMG_IN 4096     // 64*64
#define IMG_OUT 4624    // 68*68
#define N_IMG 24576     // 96*256 channel-images
#define HALO 528        // 68*68 - 64*64 border elements per image

// Neighbor-face tables, indexed by face id fi in [0,12).
// fi 0-3: north (_pn), 4-7: equator (_pe), 8-11: south (_ps).
// For equator faces, TL corner is _tl(t,lft) and BR corner is _br(b,rgt),
// so tTL/tBR entries for 4-7 are unused.
__device__ const int c_tT[12]  = {1,2,3,0,  0,1,2,3,  5,6,7,4};
__device__ const int c_tTL[12] = {2,3,0,1,  0,0,0,0,  0,1,2,3};
__device__ const int c_tL[12]  = {3,0,1,2,  3,0,1,2,  4,5,6,7};
__device__ const int c_tBL[12] = {3,0,1,2,  7,4,5,6,  11,8,9,10};
__device__ const int c_tB[12]  = {4,5,6,7,  11,8,9,10, 11,8,9,10};
__device__ const int c_tBR[12] = {8,9,10,11, 0,0,0,0,  10,11,8,9};
__device__ const int c_tR[12]  = {5,6,7,4,  8,9,10,11, 9,10,11,8};
__device__ const int c_tTR[12] = {1,2,3,0,  5,6,7,4,  9,10,11,8};

// ---------------------------------------------------------------------------
// Kernel 1: copy 64x64 interior into output center. float2 lanes (offsets are
// even but ≡2 mod 4, so float4 would be misaligned). Fully coalesced, no
// divergence.
// ---------------------------------------------------------------------------
__global__ __launch_bounds__(256) void interior_copy(const float* __restrict__ in,
                                                     float* __restrict__ out) {
    int t = blockIdx.x * 256 + threadIdx.x;   // one float2 per thread
    int n  = t >> 11;        // 2048 float2 per channel-image
    int r  = t & 2047;
    int y  = r >> 5;         // 32 float2 per row
    int c2 = r & 31;
    const float2* s = reinterpret_cast<const float2*>(in + n * IMG_IN + y * 64) + c2;
    float2 v = *s;
    float2* d = reinterpret_cast<float2*>(out + n * IMG_OUT + (y + 2) * OW + 2) + c2;
    *d = v;
}

// ---------------------------------------------------------------------------
// Kernel 2: fill the 528-element halo ring per channel-image.
// Index math derived from the JAX reference:
//   rot90(m,1)[i,j]  = m[j, 63-i]
//   rot90(m,-1)[i,j] = m[63-j, i]
//   rot90(m,2)[i,j]  = m[63-i, 63-j]
// p=2 corner blends from _tl/_br specialized below.
// ---------------------------------------------------------------------------
__device__ __forceinline__ float halo_value(const float* __restrict__ in,
                                            int bb, int ch, int fi,
                                            int oy, int ox) {
    auto ld = [&](int face, int sy, int sx) -> float {
        return in[(((bb * 12 + face) * NC + ch) * IMG_IN) + sy * 64 + sx];
    };

    const int y = oy - 2;
    const int x = ox - 2;
    const int rx = (ox < 2) ? 0 : (ox < 66 ? 1 : 2);
    const int ry = (oy < 2) ? 0 : (oy < 66 ? 1 : 2);
    const int ft = fi >> 2;   // 0=north, 1=equator, 2=south

    float v = 0.0f;

    if (ft == 0) {                              // _pn
        if (ry == 0) {
            if (rx == 1)      v = ld(c_tT[fi], x, 1 - oy);              // rot90(t,1)[-2:,:]
            else if (rx == 0) v = ld(c_tTL[fi], 1 - oy, 1 - ox);        // rot90(tl,2)[-2:,-2:]
            else              v = ld(c_tTR[fi], 62 + oy, x - 64);       // tr[-2:,:2]
        } else if (ry == 1) {
            if (rx == 0)      v = ld(c_tL[fi], 1 - ox, y);              // rot90(lft,-1)[:,-2:]
            else              v = ld(c_tR[fi], y, x - 64);              // rgt[:,:2]
        } else {
            if (rx == 1)      v = ld(c_tB[fi], y - 64, x);              // b[:2,:]
            else if (rx == 0) v = ld(c_tBL[fi], y - 64, 62 + ox);       // bl[:2,-2:]
            else              v = ld(c_tBR[fi], y - 64, x - 64);        // br[:2,:2]
        }
    } else if (ft == 1) {                       // _pe
        if (ry == 0) {
            if (rx == 1)      v = ld(c_tT[fi], 62 + oy, x);             // t[-2:,:]
            else if (rx == 2) v = ld(c_tTR[fi], 62 + oy, x - 64);       // tr[-2:,:2]
            else {                                                      // _tl(t,lft)[oy][ox]
                int r = oy, c = ox;
                if (c > r)      v = ld(c_tT[fi], 62 + r, c - r - 1);
                else if (r > c) v = ld(c_tL[fi], r - c - 1, 62 + c);
                else            v = 0.5f * (ld(c_tT[fi], 62 + r, 0) +
                                            ld(c_tL[fi], 0, 62 + r));
            }
        } else if (ry == 1) {
            if (rx == 0)      v = ld(c_tL[fi], y, 62 + ox);             // lft[:,-2:]
            else              v = ld(c_tR[fi], y, x - 64);              // rgt[:,:2]
        } else {
            if (rx == 1)      v = ld(c_tB[fi], y - 64, x);              // b[:2,:]
            else if (rx == 0) v = ld(c_tBL[fi], y - 64, 62 + ox);       // bl[:2,-2:]
            else {                                                      // _br(b,rgt)[y-64][x-64]
                int r = y - 64, c = x - 64;
                if (r > c)      v = ld(c_tB[fi], r, 64 - r + c);
                else if (c > r) v = ld(c_tR[fi], 64 - c + r, c);
                else            v = 0.5f * (ld(c_tB[fi], r, 63) +
                                            ld(c_tR[fi], 63, r));
            }
        }
    } else {                                    // _ps
        if (ry == 0) {
            if (rx == 1)      v = ld(c_tT[fi], 62 + oy, x);             // t[-2:,:]
            else if (rx == 0) v = ld(c_tTL[fi], 62 + oy, 62 + ox);      // tl[-2:,-2:]
            else              v = ld(c_tTR[fi], 62 + oy, x - 64);       // tr[-2:,:2]
        } else if (ry == 1) {
            if (rx == 0)      v = ld(c_tL[fi], y, 62 + ox);             // lft[:,-2:]
            else              v = ld(c_tR[fi], 127 - x, y);             // rot90(rgt,-1)[:,:2]
        } else {
            if (rx == 1)      v = ld(c_tB[fi], x, 127 - y);             // rot90(b,1)[:2,:]
            else if (rx == 0) v = ld(c_tBL[fi], y - 64, 62 + ox);       // bl[:2,-2:]
            else              v = ld(c_tBR[fi], 127 - y, 127 - x);      // rot90(br,2)[:2,:2]
        }
    }
    return v;
}

__global__ __launch_bounds__(256) void halo_fill(const float* __restrict__ in,
                                                 float* __restrict__ out) {
    int idx = blockIdx.x * 256 + threadIdx.x;
    if (idx >= N_IMG * HALO) return;

    int n   = idx / HALO;            // channel-image index = nf*256 + ch
    int hid = idx - n * HALO;
    int nf  = n >> 8;
    int ch  = n & 255;
    int bb  = nf / 12;
    int fi  = nf - bb * 12;

    int oy, ox;
    if (hid < 272) {                 // full rows 0,1,66,67  (4*68 = 272)
        oy = hid / 68;
        ox = hid - oy * 68;
        oy += (oy >> 1) << 6;        // 0,1 stay; 2->66, 3->67
    } else {                         // rows 2..65, cols {0,1,66,67}
        int h = hid - 272;
        oy = 2 + (h >> 2);
        int c = h & 3;
        ox = c + ((c >> 1) << 6);    // 0,1,66,67
    }

    float v = halo_value(in, bb, ch, fi, oy, ox);
    out[n * IMG_OUT + oy * OW + ox] = v;
}

extern "C" void kernel_launch(void* const* d_in, const int* in_sizes, int n_in,
                              void* d_out, int out_size, void* d_ws, size_t ws_size,
                              hipStream_t stream) {
    const float* in = (const float*)d_in[0];
    float* out = (float*)d_out;

    // Interior: 24576 images * 2048 float2 = 50,331,648 threads
    const int n_int_blocks = (N_IMG * 2048) / 256;      // 196608
    interior_copy<<<n_int_blocks, 256, 0, stream>>>(in, out);

    // Halo: 24576 images * 528 = 12,976,128 threads (exact multiple of 256)
    const int n_halo_blocks = (N_IMG * HALO) / 256;     // 50688
    halo_fill<<<n_halo_blocks, 256, 0, stream>>>(in, out);
}